// Round 15
// baseline (203.784 us; speedup 1.0000x reference)
//
#include <hip/hip_runtime.h>

typedef short s16x8 __attribute__((ext_vector_type(8)));
typedef unsigned short u16;
typedef u16 u16x8 __attribute__((ext_vector_type(8)));
typedef float f32x4 __attribute__((ext_vector_type(4)));

#define SEQ 4096
#define EMBED 1024
#define NQKV 3072

static __device__ __forceinline__ u16 f2bf(float f) {
  unsigned int u = __float_as_uint(f);
  u += 0x7fffu + ((u >> 16) & 1u);
  return (u16)(u >> 16);
}
static __device__ __forceinline__ float bf2f(u16 b) {
  return __uint_as_float(((unsigned int)b) << 16);
}

static __device__ __forceinline__ f32x4 mfma16(s16x8 a, s16x8 b, f32x4 c) {
  return __builtin_amdgcn_mfma_f32_16x16x32_bf16(a, b, c, 0, 0, 0);
}

static __device__ __forceinline__ void gl2lds(const u16* g, u16* l) {
  __builtin_amdgcn_global_load_lds(
      (const __attribute__((address_space(1))) unsigned int*)g,
      (__attribute__((address_space(3))) unsigned int*)l, 16, 0, 0);
}

#define WAITVM(n) asm volatile("s_waitcnt vmcnt(" #n ")" ::: "memory")
#define LGKM0 asm volatile("s_waitcnt lgkmcnt(0)" ::: "memory")
#define BAR() asm volatile("s_waitcnt lgkmcnt(0)\n\ts_barrier" ::: "memory")

// ---------------- Kernel 0a: x f32 -> bf16 ----------------------------------
__global__ __launch_bounds__(256) void conv_x(const float* __restrict__ x,
                                              u16* __restrict__ xbf) {
  const size_t base = ((size_t)blockIdx.x * 256 + threadIdx.x) * 16;
  u16 tmp[16];
#pragma unroll
  for (int p = 0; p < 4; ++p) {
    float4 v = *reinterpret_cast<const float4*>(&x[base + p * 4]);
    tmp[p * 4 + 0] = f2bf(v.x); tmp[p * 4 + 1] = f2bf(v.y);
    tmp[p * 4 + 2] = f2bf(v.z); tmp[p * 4 + 3] = f2bf(v.w);
  }
  *reinterpret_cast<u16x8*>(&xbf[base]) = *reinterpret_cast<u16x8*>(&tmp[0]);
  *reinterpret_cast<u16x8*>(&xbf[base + 8]) = *reinterpret_cast<u16x8*>(&tmp[8]);
}

// ---------------- Kernel 0b: W[k][n] f32 -> WT[n][k] bf16 --------------------
__global__ __launch_bounds__(256) void conv_wT(const float* __restrict__ W,
                                               u16* __restrict__ wT) {
  __shared__ u16 t[64][72];
  const int n0 = blockIdx.x * 64;
  const int k0 = blockIdx.y * 64;
  const int tid = threadIdx.x;
  const int rr = tid >> 3, c8 = (tid & 7) * 8;
#pragma unroll
  for (int p = 0; p < 2; ++p) {
    int r = p * 32 + rr;
    float4 a = *reinterpret_cast<const float4*>(&W[(size_t)(k0 + r) * NQKV + n0 + c8]);
    float4 b = *reinterpret_cast<const float4*>(&W[(size_t)(k0 + r) * NQKV + n0 + c8 + 4]);
    t[r][c8 + 0] = f2bf(a.x); t[r][c8 + 1] = f2bf(a.y);
    t[r][c8 + 2] = f2bf(a.z); t[r][c8 + 3] = f2bf(a.w);
    t[r][c8 + 4] = f2bf(b.x); t[r][c8 + 5] = f2bf(b.y);
    t[r][c8 + 6] = f2bf(b.z); t[r][c8 + 7] = f2bf(b.w);
  }
  __syncthreads();
#pragma unroll
  for (int p = 0; p < 2; ++p) {
    int c = p * 32 + rr;
    u16x8 v;
#pragma unroll
    for (int j = 0; j < 8; ++j) v[j] = t[c8 + j][c];
    *reinterpret_cast<u16x8*>(&wT[(size_t)(n0 + c) * EMBED + k0 + c8]) = v;
  }
}

// ===== 256x128 / BK=32 GEMM core — KLOOP2 sync, per-wave 128x64 (acc[8][4]) ==
// 256 thr = 4 waves; wave w: wm=w>>1 row-half, wn=w&1 col-half.
// LDS 48 KB: A bufs at 0 / 8192 elems (256x32 each, halves at +0/+4096);
//            B bufs at 16384 / 20480 (128x32 each).
// Per step: {LGKM0; stage next (6 gl2lds); WAITVM(6)} ; BAR ; 32 MFMA ; BAR.
// Proven-safe sync (R8/R14): WAITVM->BAR collective RAW; BAR's lgkm0 WAR.

// stage 128 rows x 32 elems (2 gl2lds/thread)
#define GST2(dst_off, srcbase, stride)                                        \
  {                                                                           \
    _Pragma("unroll") for (int p_ = 0; p_ < 2; ++p_) {                        \
      gl2lds((srcbase) + (size_t)(p_ * 64 + w * 16 + (l >> 2)) * (stride) +   \
                 (l & 3) * 8,                                                 \
             lds_ + (dst_off) + p_ * 2048 + w * 512);                         \
    }                                                                         \
  }

#define MFMA256(aoff, boff)                                                   \
  {                                                                           \
    s16x8 af[8], bfr[4];                                                      \
    _Pragma("unroll") for (int mi = 0; mi < 8; ++mi)                          \
        af[mi] = *reinterpret_cast<const s16x8*>(                             \
            &lds_[(aoff) + (wm * 128 + mi * 16 + lr) * 32 + lg * 8]);         \
    _Pragma("unroll") for (int nb = 0; nb < 4; ++nb)                          \
        bfr[nb] = *reinterpret_cast<const s16x8*>(                            \
            &lds_[(boff) + (wn * 64 + nb * 16 + lr) * 32 + lg * 8]);          \
    _Pragma("unroll") for (int mi = 0; mi < 8; ++mi)                          \
        _Pragma("unroll") for (int nb = 0; nb < 4; ++nb)                      \
            acc[mi][nb] = mfma16(af[mi], bfr[nb], acc[mi][nb]);               \
  }

// A staged from two independent 128-row bases (A0: rows 0-127, A1: 128-255).
#define KLOOP256(n, SRC_A0, SA0_STRIDE, SRC_A1, SA1_STRIDE, SRC_B, SB_STRIDE) \
  GST2(0, SRC_A0(0), SA0_STRIDE);                                             \
  GST2(4096, SRC_A1(0), SA1_STRIDE);                                          \
  GST2(16384, SRC_B(0), SB_STRIDE);                                           \
  for (int t = 0; t < (n); ++t) {                                             \
    const int cur_ = t & 1, nx_ = cur_ ^ 1;                                   \
    if (t + 1 < (n)) {                                                        \
      LGKM0;                                                                  \
      GST2(nx_ * 8192, SRC_A0(t + 1), SA0_STRIDE);                            \
      GST2(nx_ * 8192 + 4096, SRC_A1(t + 1), SA1_STRIDE);                     \
      GST2(16384 + nx_ * 4096, SRC_B(t + 1), SB_STRIDE);                      \
      WAITVM(6);                                                              \
    } else {                                                                  \
      WAITVM(0);                                                              \
    }                                                                         \
    BAR();                                                                    \
    MFMA256(cur_ * 8192, 16384 + cur_ * 4096);                                \
    BAR();                                                                    \
  }

#define ACC_INIT                                                              \
  f32x4 acc[8][4];                                                            \
  _Pragma("unroll") for (int i_ = 0; i_ < 8; ++i_)                            \
  _Pragma("unroll") for (int j_ = 0; j_ < 4; ++j_)                            \
      acc[i_][j_] = (f32x4){0.f, 0.f, 0.f, 0.f};

// ---------------- Kernel 1: QKV GEMM (256x128) + fused V-transpose -----------
__global__ __launch_bounds__(256) void qkv_gemm(const u16* __restrict__ xbf,
                                                const u16* __restrict__ wT,
                                                const float* __restrict__ bias,
                                                u16* __restrict__ qkv,
                                                u16* __restrict__ vT) {
  __shared__ u16 lds_[24576];  // 48 KB
  const int b = blockIdx.x;
  const int bs = (b & 7) * 48 + (b >> 3);   // XCD swizzle (384 = 8*48)
  const int bm = bs / 24, bn = bs % 24;
  const int m0 = bm * 256, n0 = bn * 128;
  const int tid = threadIdx.x;
  const int w = tid >> 6, l = tid & 63;
  const int wm = w >> 1, wn = w & 1;
  const int lg = l >> 4, lr = l & 15;

  ACC_INIT;

  const u16* xa0 = xbf + (size_t)m0 * EMBED;
  const u16* xa1 = xa0 + (size_t)128 * EMBED;
  const u16* wb = wT + (size_t)n0 * EMBED;
#define QA0(t) (xa0 + (t) * 32)
#define QA1(t) (xa1 + (t) * 32)
#define QB(t) (wb + (t) * 32)
  KLOOP256(32, QA0, EMBED, QA1, EMBED, QB, EMBED);
#undef QA0
#undef QA1
#undef QB

  if (n0 < 2 * EMBED) {
#pragma unroll
    for (int mi = 0; mi < 8; ++mi)
#pragma unroll
      for (int nb = 0; nb < 4; ++nb) {
        const int col = n0 + wn * 64 + nb * 16 + lr;
        const float bv = bias[col];
#pragma unroll
        for (int e = 0; e < 4; ++e) {
          const int row = m0 + wm * 128 + mi * 16 + lg * 4 + e;
          qkv[(size_t)row * NQKV + col] = f2bf(acc[mi][nb][e] + bv);
        }
      }
  } else {
    const int vb = n0 - 2 * EMBED;
    // two 128-row halves through LDS transpose (34 KB scratch, reuse lds_)
#pragma unroll
    for (int h = 0; h < 2; ++h) {
      __syncthreads();
      if (wm == h) {
#pragma unroll
        for (int mi = 0; mi < 8; ++mi)
#pragma unroll
          for (int nb = 0; nb < 4; ++nb) {
            const int cc = wn * 64 + nb * 16 + lr;
            const float bv = bias[n0 + cc];
#pragma unroll
            for (int e = 0; e < 4; ++e)
              lds_[(mi * 16 + lg * 4 + e) * 136 + cc] = f2bf(acc[mi][nb][e] + bv);
          }
      }
      __syncthreads();
      const int c = tid >> 1, hf = tid & 1;
#pragma unroll
      for (int j = 0; j < 8; ++j) {
        u16x8 v;
#pragma unroll
        for (int e2 = 0; e2 < 8; ++e2) v[e2] = lds_[(hf * 64 + j * 8 + e2) * 136 + c];
        *reinterpret_cast<u16x8*>(
            &vT[(size_t)(vb + c) * SEQ + m0 + h * 128 + hf * 64 + j * 8]) = v;
      }
    }
  }
}

// ---------------- Kernel 3: S = Q@K^T (scaled), 256x128 triangular -----------
// mt 0..15 (256 Q-rows), nt 0..2mt+1 (128 K-cols); 272 blocks. Output goes to
// the SAME 128-packed Sp (tile (rb,kb) at (tri(rb)+kb)*16384): half h -> rb =
// 2mt+h, guarded by nt <= rb (nt == 2mt+1 upper half is above-diagonal).
__global__ __launch_bounds__(256) void s_gemm(const u16* __restrict__ qkv,
                                              u16* __restrict__ Sp) {
  __shared__ u16 lds_[24576];
  const int b = blockIdx.x;
  const int bs = (b & 7) * 34 + (b >> 3);   // XCD swizzle (272 = 8*34)
  int mt = 0;
  while ((mt + 1) * (mt + 2) <= bs) ++mt;
  const int nt = bs - mt * (mt + 1);
  const int m0 = mt * 256, n0 = nt * 128;
  const int tid = threadIdx.x;
  const int w = tid >> 6, l = tid & 63;
  const int wm = w >> 1, wn = w & 1;
  const int lg = l >> 4, lr = l & 15;

  ACC_INIT;

  const u16* qa0 = qkv + (size_t)m0 * NQKV;
  const u16* qa1 = qa0 + (size_t)128 * NQKV;
  const u16* kb = qkv + (size_t)n0 * NQKV + EMBED;
#define SA0(t) (qa0 + (t) * 32)
#define SA1(t) (qa1 + (t) * 32)
#define SB(t) (kb + (t) * 32)
  KLOOP256(32, SA0, NQKV, SA1, NQKV, SB, NQKV);
#undef SA0
#undef SA1
#undef SB

  const int rb = 2 * mt + wm;
  if (nt <= rb) {
    u16* base = Sp + ((size_t)rb * (rb + 1) / 2 + nt) * 16384;
#pragma unroll
    for (int mi = 0; mi < 8; ++mi)
#pragma unroll
      for (int nb = 0; nb < 4; ++nb) {
        const int cn = wn * 64 + nb * 16 + lr;
#pragma unroll
        for (int e = 0; e < 4; ++e) {
          const int rm = mi * 16 + lg * 4 + e;
          base[rm * 128 + cn] = f2bf(acc[mi][nb][e] * 0.03125f);
        }
      }
  }
}

// ---------------- Kernel 4: row softmax over packed S, in place --------------
__global__ __launch_bounds__(256) void softmax_rows(u16* __restrict__ Sp) {
  __shared__ float red[8];
  const int bid = blockIdx.x;
  const int tid = threadIdx.x;
  const int w = tid >> 6, l = tid & 63;
  const float NEG = -3.0e38f;

  for (int half = 0; half < 2; ++half) {
    const int r = half ? (4095 - bid) : bid;
    const int mt = r >> 7, rr = r & 127;
    const int Lp = (mt + 1) << 7;
    const size_t tri = (size_t)mt * (mt + 1) / 2;

    float v[16];
    float mx = NEG;
#pragma unroll
    for (int s = 0; s < 2; ++s) {
      const int j = tid * 8 + s * 2048;
      if (j < Lp) {
        const u16* p = Sp + (tri + (j >> 7)) * 16384 + rr * 128 + (j & 127);
        u16x8 xv = *reinterpret_cast<const u16x8*>(p);
#pragma unroll
        for (int e = 0; e < 8; ++e) {
          float f = (j + e <= r) ? bf2f(xv[e]) : NEG;
          v[s * 8 + e] = f;
          mx = fmaxf(mx, f);
        }
      } else {
#pragma unroll
        for (int e = 0; e < 8; ++e) v[s * 8 + e] = NEG;
      }
    }
#pragma unroll
    for (int off = 32; off >= 1; off >>= 1) mx = fmaxf(mx, __shfl_xor(mx, off, 64));
    if (l == 0) red[w] = mx;
    __syncthreads();
    mx = fmaxf(fmaxf(red[0], red[1]), fmaxf(red[2], red[3]));

    float sum = 0.f;
#pragma unroll
    for (int i = 0; i < 16; ++i) {
      float e = __expf(v[i] - mx);
      v[i] = e;
      sum += e;
    }
#pragma unroll
    for (int off = 32; off >= 1; off >>= 1) sum += __shfl_xor(sum, off, 64);
    if (l == 0) red[4 + w] = sum;
    __syncthreads();
    sum = red[4] + red[5] + red[6] + red[7];
    const float inv = 1.f / sum;

#pragma unroll
    for (int s = 0; s < 2; ++s) {
      const int j = tid * 8 + s * 2048;
      if (j < Lp) {
        u16x8 pk;
#pragma unroll
        for (int e = 0; e < 8; ++e) pk[e] = f2bf(v[s * 8 + e] * inv);
        *reinterpret_cast<u16x8*>(Sp + (tri + (j >> 7)) * 16384 + rr * 128 + (j & 127)) = pk;
      }
    }
    __syncthreads();
  }
}

// ---------------- Kernel 5: O += P@V, 256x128, split-K 1024-key segments -----
// grid (40, 8): y = d-tile nt; x decodes (mt 0..15, segment); ns(mt)=(2mt+9)>>3.
// A rows span packed tiles rb=2mt (h=0) and 2mt+1 (h=1). The h=0 read at
// kb==2mt+1 would alias tile (2mt+1,0) -> staged from a zeroed page instead
// (those P entries are causally 0).
__global__ __launch_bounds__(256) void pv_gemm(const u16* __restrict__ Sp,
                                               const u16* __restrict__ vT,
                                               const u16* __restrict__ zp,
                                               float* __restrict__ out) {
  __shared__ u16 lds_[24576];
  const int nt = blockIdx.y;
  int sx = blockIdx.x;
  int mt = 0, cum = 0, ls = 0;
  for (;;) {
    const int ns = (2 * mt + 9) >> 3;
    if (sx < cum + ns) { ls = sx - cum; break; }
    cum += ns; ++mt;
  }
  const int m0 = mt * 256, n0 = nt * 128;
  const int k0 = ls * 1024;
  const int kext = (2 * mt + 2) * 128;
  const int kend = (k0 + 1024 < kext) ? (k0 + 1024) : kext;
  const int ksteps = (kend - k0) >> 5;
  const size_t tri0 = (size_t)mt * (2 * mt + 1);            // tri(2mt)
  const size_t tri1 = (size_t)(2 * mt + 1) * (mt + 1);      // tri(2mt+1)

  const int tid = threadIdx.x;
  const int w = tid >> 6, l = tid & 63;
  const int wm = w >> 1, wn = w & 1;
  const int lg = l >> 4, lr = l & 15;

  ACC_INIT;

#define PKB(t) ((k0 + (t)*32) >> 7)
#define PKC(t) ((k0 + (t)*32) & 127)
#define PA0(t) ((PKB(t) <= 2 * mt) ? (Sp + (tri0 + PKB(t)) * 16384 + PKC(t)) : zp)
#define PA1(t) (Sp + (tri1 + PKB(t)) * 16384 + PKC(t))
#define PB(t) (vT + (size_t)n0 * SEQ + k0 + (t)*32)
  KLOOP256(ksteps, PA0, 128, PA1, 128, PB, SEQ);
#undef PA0
#undef PA1
#undef PB
#undef PKB
#undef PKC

#pragma unroll
  for (int mi = 0; mi < 8; ++mi)
#pragma unroll
    for (int nb = 0; nb < 4; ++nb) {
      const int col = n0 + wn * 64 + nb * 16 + lr;
#pragma unroll
      for (int e = 0; e < 4; ++e) {
        const int row = m0 + wm * 128 + mi * 16 + lg * 4 + e;
        unsafeAtomicAdd(&out[(size_t)row * EMBED + col], acc[mi][nb][e]);
      }
    }
}

// ---------------- Fallback flash attention (small ws) ------------------------
__global__ __launch_bounds__(512) void attn_fb(const u16* __restrict__ qkv,
                                               const u16* __restrict__ vT,
                                               float* __restrict__ out) {
  __shared__ u16 q_lds[16][1032];
  __shared__ u16 kv_lds[8][3][2048];
  __shared__ u16 p_lds[16][136];
  __shared__ float redmax[8][16];
  __shared__ float redsum[8][16];
  const int bid = blockIdx.x;
  const int tid = threadIdx.x;
  const int w = tid >> 6, l = tid & 63;
  const int lg = l >> 4, lr = l & 15;

  const int sr = l >> 4;
  const int scb = (l & 15) * 16;
  const int scolA = ((scb ^ (sr << 4)) >> 1);
  const int scolB = ((scb ^ ((4 + sr) << 4)) >> 1);
  int boff[4];
#pragma unroll
  for (int kk = 0; kk < 4; ++kk)
    boff[kk] = lr * 256 + ((kk * 64 + lg * 16) ^ ((lr & 7) << 4));

  u16* kvb[3] = {&kv_lds[w][0][0], &kv_lds[w][1][0], &kv_lds[w][2][0]};

#define STAGE_K(dc, bufp)                                                     \
  {                                                                           \
    LGKM0;                                                                    \
    const u16* g0 = qkv + (size_t)(kb + w * 16 + sr) * NQKV + EMBED + (dc) * 128; \
    gl2lds(g0 + scolA, (bufp));                                               \
    gl2lds(g0 + 4 * NQKV + scolB, (bufp) + 512);                              \
    gl2lds(g0 + 8 * NQKV + scolA, (bufp) + 1024);                             \
    gl2lds(g0 + 12 * NQKV + scolB, (bufp) + 1536);                            \
  }
#define STAGE_V(j, bufp)                                                      \
  {                                                                           \
    LGKM0;                                                                    \
    const u16* g0 = vT + (size_t)((j) * 128 + w * 16 + sr) * SEQ + kb;        \
    gl2lds(g0 + scolA, (bufp));                                               \
    gl2lds(g0 + 4 * SEQ + scolB, (bufp) + 512);                               \
    gl2lds(g0 + 8 * SEQ + scolA, (bufp) + 1024);                              \
    gl2lds(g0 + 12 * SEQ + scolB, (bufp) + 1536);                             \
  }

  const int qb = bid * 16;
  __syncthreads();
#pragma unroll
  for (int p = 0; p < 4; ++p) {
    int idx = p * 512 + tid;
    int r = idx >> 7, c = (idx & 127) * 8;
    *reinterpret_cast<u16x8*>(&q_lds[r][c]) =
        *reinterpret_cast<const u16x8*>(&qkv[(size_t)(qb + r) * NQKV + c]);
  }
  __syncthreads();
  s16x8 qf[32];
#pragma unroll
  for (int kk = 0; kk < 32; ++kk)
    qf[kk] = *reinterpret_cast<const s16x8*>(&q_lds[lr][kk * 32 + lg * 8]);

  f32x4 o_acc[8];
#pragma unroll
  for (int j = 0; j < 8; ++j) o_acc[j] = (f32x4){0.f, 0.f, 0.f, 0.f};
  float m_st[4], l_st[4];
#pragma unroll
  for (int e = 0; e < 4; ++e) { m_st[e] = -__builtin_inff(); l_st[e] = 0.f; }

  const int n_it = (qb >> 7) + 1;
  for (int it = 0; it < n_it; ++it) {
    const int kb = it << 7;
    const int kcol = kb + w * 16 + lr;

    f32x4 s = (f32x4){0.f, 0.f, 0.f, 0.f};
    STAGE_K(0, kvb[0]);
    STAGE_K(1, kvb[1]);
#pragma unroll
    for (int dc = 0; dc < 8; ++dc) {
      if (dc < 6) {
        STAGE_K(dc + 2, kvb[(dc + 2) % 3]);
      } else if (dc == 6) {
        STAGE_V(0, kvb[2]);
      } else {
        STAGE_V(1, kvb[0]);
      }
      WAITVM(8);
      u16* cur = kvb[dc % 3];
#pragma unroll
      for (int kk = 0; kk < 4; ++kk) {
        s16x8 bfr = *reinterpret_cast<const s16x8*>((const char*)cur + boff[kk]);
        s = mfma16(qf[dc * 4 + kk], bfr, s);
      }
    }

    float sv[4], mx[4];
#pragma unroll
    for (int e = 0; e < 4; ++e) {
      float v = s[e] * 0.03125f;
      sv[e] = (kcol > qb + lg * 4 + e) ? -__builtin_inff() : v;
      mx[e] = sv[e];
    }
#pragma unroll
    for (int off = 1; off < 16; off <<= 1)
#pragma unroll
      for (int e = 0; e < 4; ++e) mx[e] = fmaxf(mx[e], __shfl_xor(mx[e], off, 64));
    if (lr == 0) {
#pragma unroll
      for (int e = 0; e < 4; ++e) redmax[w][lg * 4 + e] = mx[e];
    }
    BAR();

    float m_new[4], sc[4], pv[4], rs[4];
#pragma unroll
    for (int e = 0; e < 4; ++e) {
      float m = m_st[e];
#pragma unroll
      for (int ww = 0; ww < 8; ++ww) m = fmaxf(m, redmax[ww][lg * 4 + e]);
      m_new[e] = m;
      sc[e] = __expf(m_st[e] - m);
      pv[e] = __expf(sv[e] - m);
      rs[e] = pv[e];
    }
#pragma unroll
    for (int off = 1; off < 16; off <<= 1)
#pragma unroll
      for (int e = 0; e < 4; ++e) rs[e] += __shfl_xor(rs[e], off, 64);
    if (lr == 0) {
#pragma unroll
      for (int e = 0; e < 4; ++e) redsum[w][lg * 4 + e] = rs[e];
    }
#pragma unroll
    for (int e = 0; e < 4; ++e) p_lds[lg * 4 + e][w * 16 + lr] = f2bf(pv[e]);
    BAR();

#pragma unroll
    for (int e = 0; e < 4; ++e) {
      float a2 = l_st[e] * sc[e];
#pragma unroll
      for (int ww = 0; ww < 8; ++ww) a2 += redsum[ww][lg * 4 + e];
      l_st[e] = a2;
      m_st[e] = m_new[e];
    }
#pragma unroll
    for (int j = 0; j < 8; ++j)
#pragma unroll
      for (int e = 0; e < 4; ++e) o_acc[j][e] *= sc[e];

    s16x8 pa[4];
#pragma unroll
    for (int kk = 0; kk < 4; ++kk)
      pa[kk] = *reinterpret_cast<const s16x8*>(&p_lds[lr][kk * 32 + lg * 8]);

#pragma unroll
    for (int j = 0; j < 8; ++j) {
      if (j < 6) {
        STAGE_V(j + 2, kvb[(j + 4) % 3]);
        WAITVM(8);
      } else if (j == 6) {
        WAITVM(4);
      } else {
        WAITVM(0);
      }
      u16* cur = kvb[(j + 2) % 3];
#pragma unroll
      for (int kk = 0; kk < 4; ++kk) {
        s16x8 bfr = *reinterpret_cast<const s16x8*>((const char*)cur + boff[kk]);
        o_acc[j] = mfma16(pa[kk], bfr, o_acc[j]);
      }
    }
  }

#pragma unroll
  for (int j = 0; j < 8; ++j) {
    const int col = j * 128 + w * 16 + lr;
#pragma unroll
    for (int e = 0; e < 4; ++e)
      out[(size_t)(qb + lg * 4 + e) * EMBED + col] = o_acc[j][e] / l_st[e];
  }
#undef STAGE_K
#undef STAGE_V
}

extern "C" void kernel_launch(void* const* d_in, const int* in_sizes, int n_in,
                              void* d_out, int out_size, void* d_ws, size_t ws_size,
                              hipStream_t stream) {
  (void)in_sizes; (void)n_in; (void)out_size;
  const float* x = (const float*)d_in[0];
  const float* W = (const float*)d_in[1];
  const float* bias = (const float*)d_in[2];
  float* out = (float*)d_out;

  u16* qkv = (u16*)d_ws;                               // [0,24) MB
  u16* vT = qkv + (size_t)SEQ * NQKV;                  // [24,32) MB
  u16* wT = (u16*)d_out;                               // d_out[0,6) MB scratch
  u16* Sp = (u16*)((char*)d_ws + (32u << 20));         // [32, 48.5) MB packed S/P
  u16* zp = Sp + (size_t)528 * 16384;                  // 32 KB zero page after Sp

  const size_t need = (32u << 20) + (size_t)528 * 16384 * 2 + 32768;
  const bool big = ws_size >= need;
  // xbf must not alias vT (qkv_gemm reads xbf while writing vT).
  u16* xbf = big ? Sp : (u16*)((char*)d_out + (8u << 20));

  conv_x<<<(SEQ * EMBED) / (256 * 16), 256, 0, stream>>>(x, xbf);
  conv_wT<<<dim3(NQKV / 64, EMBED / 64), 256, 0, stream>>>(W, wT);
  qkv_gemm<<<384, 256, 0, stream>>>(xbf, wT, bias, qkv, vT);

  if (big) {
    hipMemsetAsync(zp, 0, 32768, stream);
    s_gemm<<<272, 256, 0, stream>>>(qkv, Sp);
    softmax_rows<<<2048, 256, 0, stream>>>(Sp);
    hipMemsetAsync(d_out, 0, (size_t)SEQ * EMBED * sizeof(float), stream);
    pv_gemm<<<dim3(40, 8), 256, 0, stream>>>(Sp, vT, zp, out);
  } else {
    attn_fb<<<SEQ / 16, 512, 0, stream>>>(qkv, vT, out);
  }
}

// Round 16
// 149.974 us; speedup vs baseline: 1.3588x; 1.3588x over previous
//
#include <hip/hip_runtime.h>

typedef short s16x8 __attribute__((ext_vector_type(8)));
typedef unsigned short u16;
typedef u16 u16x8 __attribute__((ext_vector_type(8)));
typedef float f32x4 __attribute__((ext_vector_type(4)));

#define SEQ 4096
#define EMBED 1024
#define NQKV 3072

static __device__ __forceinline__ u16 f2bf(float f) {
  unsigned int u = __float_as_uint(f);
  u += 0x7fffu + ((u >> 16) & 1u);
  return (u16)(u >> 16);
}
static __device__ __forceinline__ float bf2f(u16 b) {
  return __uint_as_float(((unsigned int)b) << 16);
}

static __device__ __forceinline__ f32x4 mfma16(s16x8 a, s16x8 b, f32x4 c) {
  return __builtin_amdgcn_mfma_f32_16x16x32_bf16(a, b, c, 0, 0, 0);
}

static __device__ __forceinline__ void gl2lds(const u16* g, u16* l) {
  __builtin_amdgcn_global_load_lds(
      (const __attribute__((address_space(1))) unsigned int*)g,
      (__attribute__((address_space(3))) unsigned int*)l, 16, 0, 0);
}

#define WAITVM(n) asm volatile("s_waitcnt vmcnt(" #n ")" ::: "memory")
#define LGKM0 asm volatile("s_waitcnt lgkmcnt(0)" ::: "memory")
#define BAR() asm volatile("s_waitcnt lgkmcnt(0)\n\ts_barrier" ::: "memory")

// ---------------- Kernel 0a: x f32 -> bf16 ----------------------------------
__global__ __launch_bounds__(256) void conv_x(const float* __restrict__ x,
                                              u16* __restrict__ xbf) {
  const size_t base = ((size_t)blockIdx.x * 256 + threadIdx.x) * 16;
  u16 tmp[16];
#pragma unroll
  for (int p = 0; p < 4; ++p) {
    float4 v = *reinterpret_cast<const float4*>(&x[base + p * 4]);
    tmp[p * 4 + 0] = f2bf(v.x); tmp[p * 4 + 1] = f2bf(v.y);
    tmp[p * 4 + 2] = f2bf(v.z); tmp[p * 4 + 3] = f2bf(v.w);
  }
  *reinterpret_cast<u16x8*>(&xbf[base]) = *reinterpret_cast<u16x8*>(&tmp[0]);
  *reinterpret_cast<u16x8*>(&xbf[base + 8]) = *reinterpret_cast<u16x8*>(&tmp[8]);
}

// ---------------- Kernel 0b: W[k][n] f32 -> WT[n][k] bf16 --------------------
__global__ __launch_bounds__(256) void conv_wT(const float* __restrict__ W,
                                               u16* __restrict__ wT) {
  __shared__ u16 t[64][72];
  const int n0 = blockIdx.x * 64;
  const int k0 = blockIdx.y * 64;
  const int tid = threadIdx.x;
  const int rr = tid >> 3, c8 = (tid & 7) * 8;
#pragma unroll
  for (int p = 0; p < 2; ++p) {
    int r = p * 32 + rr;
    float4 a = *reinterpret_cast<const float4*>(&W[(size_t)(k0 + r) * NQKV + n0 + c8]);
    float4 b = *reinterpret_cast<const float4*>(&W[(size_t)(k0 + r) * NQKV + n0 + c8 + 4]);
    t[r][c8 + 0] = f2bf(a.x); t[r][c8 + 1] = f2bf(a.y);
    t[r][c8 + 2] = f2bf(a.z); t[r][c8 + 3] = f2bf(a.w);
    t[r][c8 + 4] = f2bf(b.x); t[r][c8 + 5] = f2bf(b.y);
    t[r][c8 + 6] = f2bf(b.z); t[r][c8 + 7] = f2bf(b.w);
  }
  __syncthreads();
#pragma unroll
  for (int p = 0; p < 2; ++p) {
    int c = p * 32 + rr;
    u16x8 v;
#pragma unroll
    for (int j = 0; j < 8; ++j) v[j] = t[c8 + j][c];
    *reinterpret_cast<u16x8*>(&wT[(size_t)(n0 + c) * EMBED + k0 + c8]) = v;
  }
}

// ===== 128^2 / BK=32 GEMM core — R8's PROVEN 2-buffer 2-phase loop ==========
// Flat LDS 32 KB: A buf k at k*4096, B buf k at 8192+k*4096 (elements).
// Per step: {LGKM0; stage next; WAITVM(4)} ; BAR ; 16 MFMA ; BAR.
// WAITVM->BAR makes DMA completion collective (RAW); trailing BAR's lgkm0
// drain makes ds_read retirement collective (WAR). Do not reorder.

#define GSTAGE32(dst_off, srcbase, stride)                                    \
  {                                                                           \
    _Pragma("unroll") for (int p_ = 0; p_ < 2; ++p_) {                        \
      gl2lds((srcbase) + (size_t)(p_ * 64 + w * 16 + (l >> 2)) * (stride) +   \
                 (l & 3) * 8,                                                 \
             lds_ + (dst_off) + p_ * 2048 + w * 512);                         \
    }                                                                         \
  }

#define MFMA_STEP(aoff, boff)                                                 \
  {                                                                           \
    s16x8 af[4], bfr[4];                                                      \
    _Pragma("unroll") for (int mb = 0; mb < 4; ++mb)                          \
        af[mb] = *reinterpret_cast<const s16x8*>(                             \
            &lds_[(aoff) + (wr + mb * 16 + lr) * 32 + lg * 8]);               \
    _Pragma("unroll") for (int nb = 0; nb < 4; ++nb)                          \
        bfr[nb] = *reinterpret_cast<const s16x8*>(                            \
            &lds_[(boff) + (wc + nb * 16 + lr) * 32 + lg * 8]);               \
    _Pragma("unroll") for (int mb = 0; mb < 4; ++mb)                          \
        _Pragma("unroll") for (int nb = 0; nb < 4; ++nb)                      \
            acc[mb][nb] = mfma16(af[mb], bfr[nb], acc[mb][nb]);               \
  }

#define KLOOP2(n, SRC_A, SA_STRIDE, SRC_B, SB_STRIDE)                         \
  GSTAGE32(0, SRC_A(0), SA_STRIDE);                                           \
  GSTAGE32(8192, SRC_B(0), SB_STRIDE);                                        \
  for (int t = 0; t < (n); ++t) {                                             \
    const int cur_ = t & 1, nx_ = cur_ ^ 1;                                   \
    if (t + 1 < (n)) {                                                        \
      LGKM0;                                                                  \
      GSTAGE32(nx_ * 4096, SRC_A(t + 1), SA_STRIDE);                          \
      GSTAGE32(8192 + nx_ * 4096, SRC_B(t + 1), SB_STRIDE);                   \
      WAITVM(4);                                                              \
    } else {                                                                  \
      WAITVM(0);                                                              \
    }                                                                         \
    BAR();                                                                    \
    MFMA_STEP(cur_ * 4096, 8192 + cur_ * 4096);                               \
    BAR();                                                                    \
  }

// ---------------- Kernel 1: QKV GEMM + fused V-transpose ---------------------
// Q,K tiles (n0 < 2048) -> qkv[row][col]; V tiles (n0 >= 2048) -> vT[col][row]
// via LDS transpose in the epilogue. qkv cols [2048,3072) are never written.
__global__ __launch_bounds__(256) void qkv_gemm(const u16* __restrict__ xbf,
                                                const u16* __restrict__ wT,
                                                const float* __restrict__ bias,
                                                u16* __restrict__ qkv,
                                                u16* __restrict__ vT) {
  __shared__ u16 lds_[17408];  // 34 KB (K-loop uses 32 KB; epilogue 128x136)
  const int b = blockIdx.x;
  const int bs = (b & 7) * 96 + (b >> 3);   // XCD swizzle (768 % 8 == 0)
  const int bm = bs / 24, bn = bs % 24;
  const int m0 = bm * 128, n0 = bn * 128;
  const int tid = threadIdx.x;
  const int w = tid >> 6, l = tid & 63;
  const int wr = (w >> 1) * 64, wc = (w & 1) * 64;
  const int lg = l >> 4, lr = l & 15;

  f32x4 acc[4][4];
#pragma unroll
  for (int i = 0; i < 4; ++i)
#pragma unroll
    for (int j = 0; j < 4; ++j) acc[i][j] = (f32x4){0.f, 0.f, 0.f, 0.f};

  const u16* xa = xbf + (size_t)m0 * EMBED;
  const u16* wb = wT + (size_t)n0 * EMBED;
#define QA_SRC(t) (xa + (t) * 32)
#define QB_SRC(t) (wb + (t) * 32)
  KLOOP2(32, QA_SRC, EMBED, QB_SRC, EMBED);
#undef QA_SRC
#undef QB_SRC

  if (n0 < 2 * EMBED) {
#pragma unroll
    for (int mb = 0; mb < 4; ++mb)
#pragma unroll
      for (int nb = 0; nb < 4; ++nb) {
        const int col = n0 + wc + nb * 16 + lr;
        const float bv = bias[col];
#pragma unroll
        for (int e = 0; e < 4; ++e) {
          const int row = m0 + wr + mb * 16 + lg * 4 + e;
          qkv[(size_t)row * NQKV + col] = f2bf(acc[mb][nb][e] + bv);
        }
      }
  } else {
    const int vb = n0 - 2 * EMBED;
    __syncthreads();  // K-loop LDS reads all retired; reuse lds_ as scratch
#pragma unroll
    for (int mb = 0; mb < 4; ++mb)
#pragma unroll
      for (int nb = 0; nb < 4; ++nb) {
        const int cc = wc + nb * 16 + lr;
        const float bv = bias[n0 + cc];
#pragma unroll
        for (int e = 0; e < 4; ++e)
          lds_[(wr + mb * 16 + lg * 4 + e) * 136 + cc] = f2bf(acc[mb][nb][e] + bv);
      }
    __syncthreads();
    const int c = tid >> 1, hf = tid & 1;
#pragma unroll
    for (int j = 0; j < 8; ++j) {
      u16x8 v;
#pragma unroll
      for (int e2 = 0; e2 < 8; ++e2) v[e2] = lds_[(hf * 64 + j * 8 + e2) * 136 + c];
      *reinterpret_cast<u16x8*>(&vT[(size_t)(vb + c) * SEQ + m0 + hf * 64 + j * 8]) = v;
    }
  }
}

// ---------------- Kernel 3: S = Q @ K^T (scaled), triangular tiles -----------
__global__ __launch_bounds__(256) void s_gemm(const u16* __restrict__ qkv,
                                              u16* __restrict__ Sp) {
  __shared__ u16 lds_[16384];
  const int b = blockIdx.x;
  const int bs = (b & 7) * 66 + (b >> 3);   // XCD swizzle (528 = 8*66)
  int mt = 0, cum = 0;
  while (cum + mt + 1 <= bs) { cum += mt + 1; ++mt; }
  const int nt = bs - cum;
  const int m0 = mt * 128, n0 = nt * 128;
  const int tid = threadIdx.x;
  const int w = tid >> 6, l = tid & 63;
  const int wr = (w >> 1) * 64, wc = (w & 1) * 64;
  const int lg = l >> 4, lr = l & 15;

  f32x4 acc[4][4];
#pragma unroll
  for (int i = 0; i < 4; ++i)
#pragma unroll
    for (int j = 0; j < 4; ++j) acc[i][j] = (f32x4){0.f, 0.f, 0.f, 0.f};

  const u16* qa = qkv + (size_t)m0 * NQKV;           // Q rows
  const u16* kb = qkv + (size_t)n0 * NQKV + EMBED;   // K rows
#define SA_SRC(t) (qa + (t) * 32)
#define SB_SRC(t) (kb + (t) * 32)
  KLOOP2(32, SA_SRC, NQKV, SB_SRC, NQKV);
#undef SA_SRC
#undef SB_SRC

  u16* base = Sp + (size_t)bs * 16384;
#pragma unroll
  for (int mb = 0; mb < 4; ++mb)
#pragma unroll
    for (int nb = 0; nb < 4; ++nb) {
      const int cn = wc + nb * 16 + lr;
#pragma unroll
      for (int e = 0; e < 4; ++e) {
        const int rm = wr + mb * 16 + lg * 4 + e;
        base[rm * 128 + cn] = f2bf(acc[mb][nb][e] * 0.03125f);
      }
    }
}

// ---------------- Kernel 4: row softmax over packed S, in place --------------
__global__ __launch_bounds__(256) void softmax_rows(u16* __restrict__ Sp) {
  __shared__ float red[8];
  const int bid = blockIdx.x;
  const int tid = threadIdx.x;
  const int w = tid >> 6, l = tid & 63;
  const float NEG = -3.0e38f;

  for (int half = 0; half < 2; ++half) {
    const int r = half ? (4095 - bid) : bid;
    const int mt = r >> 7, rr = r & 127;
    const int Lp = (mt + 1) << 7;
    const size_t tri = (size_t)mt * (mt + 1) / 2;

    float v[16];
    float mx = NEG;
#pragma unroll
    for (int s = 0; s < 2; ++s) {
      const int j = tid * 8 + s * 2048;
      if (j < Lp) {
        const u16* p = Sp + (tri + (j >> 7)) * 16384 + rr * 128 + (j & 127);
        u16x8 xv = *reinterpret_cast<const u16x8*>(p);
#pragma unroll
        for (int e = 0; e < 8; ++e) {
          float f = (j + e <= r) ? bf2f(xv[e]) : NEG;
          v[s * 8 + e] = f;
          mx = fmaxf(mx, f);
        }
      } else {
#pragma unroll
        for (int e = 0; e < 8; ++e) v[s * 8 + e] = NEG;
      }
    }
#pragma unroll
    for (int off = 32; off >= 1; off >>= 1) mx = fmaxf(mx, __shfl_xor(mx, off, 64));
    if (l == 0) red[w] = mx;
    __syncthreads();
    mx = fmaxf(fmaxf(red[0], red[1]), fmaxf(red[2], red[3]));

    float sum = 0.f;
#pragma unroll
    for (int i = 0; i < 16; ++i) {
      float e = __expf(v[i] - mx);
      v[i] = e;
      sum += e;
    }
#pragma unroll
    for (int off = 32; off >= 1; off >>= 1) sum += __shfl_xor(sum, off, 64);
    if (l == 0) red[4 + w] = sum;
    __syncthreads();
    sum = red[4] + red[5] + red[6] + red[7];
    const float inv = 1.f / sum;

#pragma unroll
    for (int s = 0; s < 2; ++s) {
      const int j = tid * 8 + s * 2048;
      if (j < Lp) {
        u16x8 pk;
#pragma unroll
        for (int e = 0; e < 8; ++e) pk[e] = f2bf(v[s * 8 + e] * inv);
        *reinterpret_cast<u16x8*>(Sp + (tri + (j >> 7)) * 16384 + rr * 128 + (j & 127)) = pk;
      }
    }
    __syncthreads();
  }
}

// ---------------- Kernel 5: O += P @ V, split-K 1024-key segments ------------
// grid (80, 8): y = d-tile nt, x decodes (mt, segment); ns(mt) = (mt+8)>>3.
__global__ __launch_bounds__(256) void pv_gemm(const u16* __restrict__ Sp,
                                               const u16* __restrict__ vT,
                                               float* __restrict__ out) {
  __shared__ u16 lds_[16384];
  const int nt = blockIdx.y;
  int s81 = blockIdx.x;
  int mt = 0, cum = 0, ls = 0;
  for (;;) {
    const int ns = (mt + 8) >> 3;
    if (s81 < cum + ns) { ls = s81 - cum; break; }
    cum += ns; ++mt;
  }
  const int m0 = mt * 128, n0 = nt * 128;
  const int k0 = ls * 1024;
  const int kext = (mt + 1) * 128;
  const int kend = (k0 + 1024 < kext) ? (k0 + 1024) : kext;
  const int ksteps = (kend - k0) >> 5;
  const size_t tri = (size_t)mt * (mt + 1) / 2;

  const int tid = threadIdx.x;
  const int w = tid >> 6, l = tid & 63;
  const int wr = (w >> 1) * 64, wc = (w & 1) * 64;
  const int lg = l >> 4, lr = l & 15;

  f32x4 acc[4][4];
#pragma unroll
  for (int i = 0; i < 4; ++i)
#pragma unroll
    for (int j = 0; j < 4; ++j) acc[i][j] = (f32x4){0.f, 0.f, 0.f, 0.f};

#define PA_SRC(t) (Sp + (tri + ((k0 + (t)*32) >> 7)) * 16384 + ((k0 + (t)*32) & 127))
#define PB_SRC(t) (vT + (size_t)n0 * SEQ + k0 + (t)*32)
  KLOOP2(ksteps, PA_SRC, 128, PB_SRC, SEQ);
#undef PA_SRC
#undef PB_SRC

#pragma unroll
  for (int mb = 0; mb < 4; ++mb)
#pragma unroll
    for (int nb = 0; nb < 4; ++nb) {
      const int col = n0 + wc + nb * 16 + lr;
#pragma unroll
      for (int e = 0; e < 4; ++e) {
        const int row = m0 + wr + mb * 16 + lg * 4 + e;
        unsafeAtomicAdd(&out[(size_t)row * EMBED + col], acc[mb][nb][e]);
      }
    }
}

// ---------------- Fallback flash attention (small ws) ------------------------
__global__ __launch_bounds__(512) void attn_fb(const u16* __restrict__ qkv,
                                               const u16* __restrict__ vT,
                                               float* __restrict__ out) {
  __shared__ u16 q_lds[16][1032];
  __shared__ u16 kv_lds[8][3][2048];
  __shared__ u16 p_lds[16][136];
  __shared__ float redmax[8][16];
  __shared__ float redsum[8][16];
  const int bid = blockIdx.x;
  const int tid = threadIdx.x;
  const int w = tid >> 6, l = tid & 63;
  const int lg = l >> 4, lr = l & 15;

  const int sr = l >> 4;
  const int scb = (l & 15) * 16;
  const int scolA = ((scb ^ (sr << 4)) >> 1);
  const int scolB = ((scb ^ ((4 + sr) << 4)) >> 1);
  int boff[4];
#pragma unroll
  for (int kk = 0; kk < 4; ++kk)
    boff[kk] = lr * 256 + ((kk * 64 + lg * 16) ^ ((lr & 7) << 4));

  u16* kvb[3] = {&kv_lds[w][0][0], &kv_lds[w][1][0], &kv_lds[w][2][0]};

#define STAGE_K(dc, bufp)                                                     \
  {                                                                           \
    LGKM0;                                                                    \
    const u16* g0 = qkv + (size_t)(kb + w * 16 + sr) * NQKV + EMBED + (dc) * 128; \
    gl2lds(g0 + scolA, (bufp));                                               \
    gl2lds(g0 + 4 * NQKV + scolB, (bufp) + 512);                              \
    gl2lds(g0 + 8 * NQKV + scolA, (bufp) + 1024);                             \
    gl2lds(g0 + 12 * NQKV + scolB, (bufp) + 1536);                            \
  }
#define STAGE_V(j, bufp)                                                      \
  {                                                                           \
    LGKM0;                                                                    \
    const u16* g0 = vT + (size_t)((j) * 128 + w * 16 + sr) * SEQ + kb;        \
    gl2lds(g0 + scolA, (bufp));                                               \
    gl2lds(g0 + 4 * SEQ + scolB, (bufp) + 512);                               \
    gl2lds(g0 + 8 * SEQ + scolA, (bufp) + 1024);                              \
    gl2lds(g0 + 12 * SEQ + scolB, (bufp) + 1536);                             \
  }

  const int qb = bid * 16;
  __syncthreads();
#pragma unroll
  for (int p = 0; p < 4; ++p) {
    int idx = p * 512 + tid;
    int r = idx >> 7, c = (idx & 127) * 8;
    *reinterpret_cast<u16x8*>(&q_lds[r][c]) =
        *reinterpret_cast<const u16x8*>(&qkv[(size_t)(qb + r) * NQKV + c]);
  }
  __syncthreads();
  s16x8 qf[32];
#pragma unroll
  for (int kk = 0; kk < 32; ++kk)
    qf[kk] = *reinterpret_cast<const s16x8*>(&q_lds[lr][kk * 32 + lg * 8]);

  f32x4 o_acc[8];
#pragma unroll
  for (int j = 0; j < 8; ++j) o_acc[j] = (f32x4){0.f, 0.f, 0.f, 0.f};
  float m_st[4], l_st[4];
#pragma unroll
  for (int e = 0; e < 4; ++e) { m_st[e] = -__builtin_inff(); l_st[e] = 0.f; }

  const int n_it = (qb >> 7) + 1;
  for (int it = 0; it < n_it; ++it) {
    const int kb = it << 7;
    const int kcol = kb + w * 16 + lr;

    f32x4 s = (f32x4){0.f, 0.f, 0.f, 0.f};
    STAGE_K(0, kvb[0]);
    STAGE_K(1, kvb[1]);
#pragma unroll
    for (int dc = 0; dc < 8; ++dc) {
      if (dc < 6) {
        STAGE_K(dc + 2, kvb[(dc + 2) % 3]);
      } else if (dc == 6) {
        STAGE_V(0, kvb[2]);
      } else {
        STAGE_V(1, kvb[0]);
      }
      WAITVM(8);
      u16* cur = kvb[dc % 3];
#pragma unroll
      for (int kk = 0; kk < 4; ++kk) {
        s16x8 bfr = *reinterpret_cast<const s16x8*>((const char*)cur + boff[kk]);
        s = mfma16(qf[dc * 4 + kk], bfr, s);
      }
    }

    float sv[4], mx[4];
#pragma unroll
    for (int e = 0; e < 4; ++e) {
      float v = s[e] * 0.03125f;
      sv[e] = (kcol > qb + lg * 4 + e) ? -__builtin_inff() : v;
      mx[e] = sv[e];
    }
#pragma unroll
    for (int off = 1; off < 16; off <<= 1)
#pragma unroll
      for (int e = 0; e < 4; ++e) mx[e] = fmaxf(mx[e], __shfl_xor(mx[e], off, 64));
    if (lr == 0) {
#pragma unroll
      for (int e = 0; e < 4; ++e) redmax[w][lg * 4 + e] = mx[e];
    }
    BAR();

    float m_new[4], sc[4], pv[4], rs[4];
#pragma unroll
    for (int e = 0; e < 4; ++e) {
      float m = m_st[e];
#pragma unroll
      for (int ww = 0; ww < 8; ++ww) m = fmaxf(m, redmax[ww][lg * 4 + e]);
      m_new[e] = m;
      sc[e] = __expf(m_st[e] - m);
      pv[e] = __expf(sv[e] - m);
      rs[e] = pv[e];
    }
#pragma unroll
    for (int off = 1; off < 16; off <<= 1)
#pragma unroll
      for (int e = 0; e < 4; ++e) rs[e] += __shfl_xor(rs[e], off, 64);
    if (lr == 0) {
#pragma unroll
      for (int e = 0; e < 4; ++e) redsum[w][lg * 4 + e] = rs[e];
    }
#pragma unroll
    for (int e = 0; e < 4; ++e) p_lds[lg * 4 + e][w * 16 + lr] = f2bf(pv[e]);
    BAR();

#pragma unroll
    for (int e = 0; e < 4; ++e) {
      float a2 = l_st[e] * sc[e];
#pragma unroll
      for (int ww = 0; ww < 8; ++ww) a2 += redsum[ww][lg * 4 + e];
      l_st[e] = a2;
      m_st[e] = m_new[e];
    }
#pragma unroll
    for (int j = 0; j < 8; ++j)
#pragma unroll
      for (int e = 0; e < 4; ++e) o_acc[j][e] *= sc[e];

    s16x8 pa[4];
#pragma unroll
    for (int kk = 0; kk < 4; ++kk)
      pa[kk] = *reinterpret_cast<const s16x8*>(&p_lds[lr][kk * 32 + lg * 8]);

#pragma unroll
    for (int j = 0; j < 8; ++j) {
      if (j < 6) {
        STAGE_V(j + 2, kvb[(j + 4) % 3]);
        WAITVM(8);
      } else if (j == 6) {
        WAITVM(4);
      } else {
        WAITVM(0);
      }
      u16* cur = kvb[(j + 2) % 3];
#pragma unroll
      for (int kk = 0; kk < 4; ++kk) {
        s16x8 bfr = *reinterpret_cast<const s16x8*>((const char*)cur + boff[kk]);
        o_acc[j] = mfma16(pa[kk], bfr, o_acc[j]);
      }
    }
  }

#pragma unroll
  for (int j = 0; j < 8; ++j) {
    const int col = j * 128 + w * 16 + lr;
#pragma unroll
    for (int e = 0; e < 4; ++e)
      out[(size_t)(qb + lg * 4 + e) * EMBED + col] = o_acc[j][e] / l_st[e];
  }
#undef STAGE_K
#undef STAGE_V
}

extern "C" void kernel_launch(void* const* d_in, const int* in_sizes, int n_in,
                              void* d_out, int out_size, void* d_ws, size_t ws_size,
                              hipStream_t stream) {
  (void)in_sizes; (void)n_in; (void)out_size;
  const float* x = (const float*)d_in[0];
  const float* W = (const float*)d_in[1];
  const float* bias = (const float*)d_in[2];
  float* out = (float*)d_out;

  u16* qkv = (u16*)d_ws;                               // [0,24) MB
  u16* vT = qkv + (size_t)SEQ * NQKV;                  // [24,32) MB
  u16* wT = (u16*)d_out;                               // d_out[0,6) MB scratch (dead after qkv_gemm)
  u16* Sp = (u16*)((char*)d_ws + (32u << 20));         // [32, 48.5) MB packed S/P

  const size_t need = (32u << 20) + (size_t)528 * 16384 * 2;
  const bool big = ws_size >= need;
  // xbf must not alias vT (qkv_gemm reads xbf while writing vT).
  // big: use Sp region (dead until s_gemm). small: use d_out[8,16) MB
  // (attn_fb overwrites all of d_out afterwards).
  u16* xbf = big ? Sp : (u16*)((char*)d_out + (8u << 20));

  conv_x<<<(SEQ * EMBED) / (256 * 16), 256, 0, stream>>>(x, xbf);
  conv_wT<<<dim3(NQKV / 64, EMBED / 64), 256, 0, stream>>>(W, wT);
  qkv_gemm<<<(SEQ / 128) * (NQKV / 128), 256, 0, stream>>>(xbf, wT, bias, qkv, vT);

  if (big) {
    s_gemm<<<528, 256, 0, stream>>>(qkv, Sp);
    softmax_rows<<<2048, 256, 0, stream>>>(Sp);
    hipMemsetAsync(d_out, 0, (size_t)SEQ * EMBED * sizeof(float), stream);
    pv_gemm<<<dim3(80, 8), 256, 0, stream>>>(Sp, vT, out);
  } else {
    attn_fb<<<SEQ / 16, 512, 0, stream>>>(qkv, vT, out);
  }
}

// Round 17
// 146.081 us; speedup vs baseline: 1.3950x; 1.0266x over previous
//
#include <hip/hip_runtime.h>

typedef short s16x8 __attribute__((ext_vector_type(8)));
typedef unsigned short u16;
typedef u16 u16x8 __attribute__((ext_vector_type(8)));
typedef float f32x4 __attribute__((ext_vector_type(4)));

#define SEQ 4096
#define EMBED 1024
#define NQKV 3072

static __device__ __forceinline__ u16 f2bf(float f) {
  unsigned int u = __float_as_uint(f);
  u += 0x7fffu + ((u >> 16) & 1u);
  return (u16)(u >> 16);
}
static __device__ __forceinline__ float bf2f(u16 b) {
  return __uint_as_float(((unsigned int)b) << 16);
}

static __device__ __forceinline__ f32x4 mfma16(s16x8 a, s16x8 b, f32x4 c) {
  return __builtin_amdgcn_mfma_f32_16x16x32_bf16(a, b, c, 0, 0, 0);
}

static __device__ __forceinline__ void gl2lds(const u16* g, u16* l) {
  __builtin_amdgcn_global_load_lds(
      (const __attribute__((address_space(1))) unsigned int*)g,
      (__attribute__((address_space(3))) unsigned int*)l, 16, 0, 0);
}

#define WAITVM(n) asm volatile("s_waitcnt vmcnt(" #n ")" ::: "memory")
#define LGKM0 asm volatile("s_waitcnt lgkmcnt(0)" ::: "memory")
#define BAR() asm volatile("s_waitcnt lgkmcnt(0)\n\ts_barrier" ::: "memory")

// ---------------- Kernel 0: fused input conversion ---------------------------
// blocks [0,1024): x f32 -> bf16 flat. blocks [1024,1792): W -> WT bf16.
__global__ __launch_bounds__(256) void conv_fused(const float* __restrict__ x,
                                                  const float* __restrict__ W,
                                                  u16* __restrict__ xbf,
                                                  u16* __restrict__ wT) {
  __shared__ u16 t[64][72];
  const int tid = threadIdx.x;
  if (blockIdx.x < 1024) {
    const size_t base = ((size_t)blockIdx.x * 256 + tid) * 16;
    u16 tmp[16];
#pragma unroll
    for (int p = 0; p < 4; ++p) {
      float4 v = *reinterpret_cast<const float4*>(&x[base + p * 4]);
      tmp[p * 4 + 0] = f2bf(v.x); tmp[p * 4 + 1] = f2bf(v.y);
      tmp[p * 4 + 2] = f2bf(v.z); tmp[p * 4 + 3] = f2bf(v.w);
    }
    *reinterpret_cast<u16x8*>(&xbf[base]) = *reinterpret_cast<u16x8*>(&tmp[0]);
    *reinterpret_cast<u16x8*>(&xbf[base + 8]) = *reinterpret_cast<u16x8*>(&tmp[8]);
  } else {
    const int b2 = blockIdx.x - 1024;
    const int n0 = (b2 % 48) * 64;
    const int k0 = (b2 / 48) * 64;
    const int rr = tid >> 3, c8 = (tid & 7) * 8;
#pragma unroll
    for (int p = 0; p < 2; ++p) {
      int r = p * 32 + rr;
      float4 a = *reinterpret_cast<const float4*>(&W[(size_t)(k0 + r) * NQKV + n0 + c8]);
      float4 b = *reinterpret_cast<const float4*>(&W[(size_t)(k0 + r) * NQKV + n0 + c8 + 4]);
      t[r][c8 + 0] = f2bf(a.x); t[r][c8 + 1] = f2bf(a.y);
      t[r][c8 + 2] = f2bf(a.z); t[r][c8 + 3] = f2bf(a.w);
      t[r][c8 + 4] = f2bf(b.x); t[r][c8 + 5] = f2bf(b.y);
      t[r][c8 + 6] = f2bf(b.z); t[r][c8 + 7] = f2bf(b.w);
    }
    __syncthreads();
#pragma unroll
    for (int p = 0; p < 2; ++p) {
      int c = p * 32 + rr;
      u16x8 v;
#pragma unroll
      for (int j = 0; j < 8; ++j) v[j] = t[c8 + j][c];
      *reinterpret_cast<u16x8*>(&wT[(size_t)(n0 + c) * EMBED + k0 + c8]) = v;
    }
  }
}

// ===== 128^2 / BK=32 GEMM core — R8's PROVEN 2-buffer 2-phase loop ==========
// Per step: {LGKM0; stage next; WAITVM(4)} ; BAR ; 16 MFMA ; BAR.
// WAITVM->BAR makes DMA completion collective (RAW); BAR's lgkm0 drain makes
// ds_read retirement collective (WAR). Do not reorder.

#define GSTAGE32(dst_off, srcbase, stride)                                    \
  {                                                                           \
    _Pragma("unroll") for (int p_ = 0; p_ < 2; ++p_) {                        \
      gl2lds((srcbase) + (size_t)(p_ * 64 + w * 16 + (l >> 2)) * (stride) +   \
                 (l & 3) * 8,                                                 \
             lds_ + (dst_off) + p_ * 2048 + w * 512);                         \
    }                                                                         \
  }

#define MFMA_STEP(aoff, boff)                                                 \
  {                                                                           \
    s16x8 af[4], bfr[4];                                                      \
    _Pragma("unroll") for (int mb = 0; mb < 4; ++mb)                          \
        af[mb] = *reinterpret_cast<const s16x8*>(                             \
            &lds_[(aoff) + (wr + mb * 16 + lr) * 32 + lg * 8]);               \
    _Pragma("unroll") for (int nb = 0; nb < 4; ++nb)                          \
        bfr[nb] = *reinterpret_cast<const s16x8*>(                            \
            &lds_[(boff) + (wc + nb * 16 + lr) * 32 + lg * 8]);               \
    _Pragma("unroll") for (int mb = 0; mb < 4; ++mb)                          \
        _Pragma("unroll") for (int nb = 0; nb < 4; ++nb)                      \
            acc[mb][nb] = mfma16(af[mb], bfr[nb], acc[mb][nb]);               \
  }

#define KLOOP2(n, SRC_A, SA_STRIDE, SRC_B, SB_STRIDE)                         \
  GSTAGE32(0, SRC_A(0), SA_STRIDE);                                           \
  GSTAGE32(8192, SRC_B(0), SB_STRIDE);                                        \
  for (int t = 0; t < (n); ++t) {                                             \
    const int cur_ = t & 1, nx_ = cur_ ^ 1;                                   \
    if (t + 1 < (n)) {                                                        \
      LGKM0;                                                                  \
      GSTAGE32(nx_ * 4096, SRC_A(t + 1), SA_STRIDE);                          \
      GSTAGE32(8192 + nx_ * 4096, SRC_B(t + 1), SB_STRIDE);                   \
      WAITVM(4);                                                              \
    } else {                                                                  \
      WAITVM(0);                                                              \
    }                                                                         \
    BAR();                                                                    \
    MFMA_STEP(cur_ * 4096, 8192 + cur_ * 4096);                               \
    BAR();                                                                    \
  }

// ---------------- Kernel 1: QKV GEMM + fused V-transpose ---------------------
__global__ __launch_bounds__(256) void qkv_gemm(const u16* __restrict__ xbf,
                                                const u16* __restrict__ wT,
                                                const float* __restrict__ bias,
                                                u16* __restrict__ qkv,
                                                u16* __restrict__ vT) {
  __shared__ u16 lds_[17408];  // 34 KB (K-loop uses 32 KB; epilogue 128x136)
  const int b = blockIdx.x;
  const int bs = (b & 7) * 96 + (b >> 3);   // XCD swizzle (768 % 8 == 0)
  const int bm = bs / 24, bn = bs % 24;
  const int m0 = bm * 128, n0 = bn * 128;
  const int tid = threadIdx.x;
  const int w = tid >> 6, l = tid & 63;
  const int wr = (w >> 1) * 64, wc = (w & 1) * 64;
  const int lg = l >> 4, lr = l & 15;

  f32x4 acc[4][4];
#pragma unroll
  for (int i = 0; i < 4; ++i)
#pragma unroll
    for (int j = 0; j < 4; ++j) acc[i][j] = (f32x4){0.f, 0.f, 0.f, 0.f};

  const u16* xa = xbf + (size_t)m0 * EMBED;
  const u16* wb = wT + (size_t)n0 * EMBED;
#define QA_SRC(t) (xa + (t) * 32)
#define QB_SRC(t) (wb + (t) * 32)
  KLOOP2(32, QA_SRC, EMBED, QB_SRC, EMBED);
#undef QA_SRC
#undef QB_SRC

  if (n0 < 2 * EMBED) {
#pragma unroll
    for (int mb = 0; mb < 4; ++mb)
#pragma unroll
      for (int nb = 0; nb < 4; ++nb) {
        const int col = n0 + wc + nb * 16 + lr;
        const float bv = bias[col];
#pragma unroll
        for (int e = 0; e < 4; ++e) {
          const int row = m0 + wr + mb * 16 + lg * 4 + e;
          qkv[(size_t)row * NQKV + col] = f2bf(acc[mb][nb][e] + bv);
        }
      }
  } else {
    const int vb = n0 - 2 * EMBED;
    __syncthreads();  // K-loop LDS reads all retired; reuse lds_ as scratch
#pragma unroll
    for (int mb = 0; mb < 4; ++mb)
#pragma unroll
      for (int nb = 0; nb < 4; ++nb) {
        const int cc = wc + nb * 16 + lr;
        const float bv = bias[n0 + cc];
#pragma unroll
        for (int e = 0; e < 4; ++e)
          lds_[(wr + mb * 16 + lg * 4 + e) * 136 + cc] = f2bf(acc[mb][nb][e] + bv);
      }
    __syncthreads();
    const int c = tid >> 1, hf = tid & 1;
#pragma unroll
    for (int j = 0; j < 8; ++j) {
      u16x8 v;
#pragma unroll
      for (int e2 = 0; e2 < 8; ++e2) v[e2] = lds_[(hf * 64 + j * 8 + e2) * 136 + c];
      *reinterpret_cast<u16x8*>(&vT[(size_t)(vb + c) * SEQ + m0 + hf * 64 + j * 8]) = v;
    }
  }
}

// ---------------- Kernel 3: S = Q @ K^T (scaled), triangular tiles -----------
__global__ __launch_bounds__(256) void s_gemm(const u16* __restrict__ qkv,
                                              u16* __restrict__ Sp) {
  __shared__ u16 lds_[16384];
  const int b = blockIdx.x;
  const int bs = (b & 7) * 66 + (b >> 3);   // XCD swizzle (528 = 8*66)
  int mt = 0, cum = 0;
  while (cum + mt + 1 <= bs) { cum += mt + 1; ++mt; }
  const int nt = bs - cum;
  const int m0 = mt * 128, n0 = nt * 128;
  const int tid = threadIdx.x;
  const int w = tid >> 6, l = tid & 63;
  const int wr = (w >> 1) * 64, wc = (w & 1) * 64;
  const int lg = l >> 4, lr = l & 15;

  f32x4 acc[4][4];
#pragma unroll
  for (int i = 0; i < 4; ++i)
#pragma unroll
    for (int j = 0; j < 4; ++j) acc[i][j] = (f32x4){0.f, 0.f, 0.f, 0.f};

  const u16* qa = qkv + (size_t)m0 * NQKV;           // Q rows
  const u16* kb = qkv + (size_t)n0 * NQKV + EMBED;   // K rows
#define SA_SRC(t) (qa + (t) * 32)
#define SB_SRC(t) (kb + (t) * 32)
  KLOOP2(32, SA_SRC, NQKV, SB_SRC, NQKV);
#undef SA_SRC
#undef SB_SRC

  u16* base = Sp + (size_t)bs * 16384;
#pragma unroll
  for (int mb = 0; mb < 4; ++mb)
#pragma unroll
    for (int nb = 0; nb < 4; ++nb) {
      const int cn = wc + nb * 16 + lr;
#pragma unroll
      for (int e = 0; e < 4; ++e) {
        const int rm = wr + mb * 16 + lg * 4 + e;
        base[rm * 128 + cn] = f2bf(acc[mb][nb][e] * 0.03125f);
      }
    }
}

// ---------------- Kernel 4: row softmax over packed S, in place --------------
__global__ __launch_bounds__(256) void softmax_rows(u16* __restrict__ Sp) {
  __shared__ float red[8];
  const int bid = blockIdx.x;
  const int tid = threadIdx.x;
  const int w = tid >> 6, l = tid & 63;
  const float NEG = -3.0e38f;

  for (int half = 0; half < 2; ++half) {
    const int r = half ? (4095 - bid) : bid;
    const int mt = r >> 7, rr = r & 127;
    const int Lp = (mt + 1) << 7;
    const size_t tri = (size_t)mt * (mt + 1) / 2;

    float v[16];
    float mx = NEG;
#pragma unroll
    for (int s = 0; s < 2; ++s) {
      const int j = tid * 8 + s * 2048;
      if (j < Lp) {
        const u16* p = Sp + (tri + (j >> 7)) * 16384 + rr * 128 + (j & 127);
        u16x8 xv = *reinterpret_cast<const u16x8*>(p);
#pragma unroll
        for (int e = 0; e < 8; ++e) {
          float f = (j + e <= r) ? bf2f(xv[e]) : NEG;
          v[s * 8 + e] = f;
          mx = fmaxf(mx, f);
        }
      } else {
#pragma unroll
        for (int e = 0; e < 8; ++e) v[s * 8 + e] = NEG;
      }
    }
#pragma unroll
    for (int off = 32; off >= 1; off >>= 1) mx = fmaxf(mx, __shfl_xor(mx, off, 64));
    if (l == 0) red[w] = mx;
    __syncthreads();
    mx = fmaxf(fmaxf(red[0], red[1]), fmaxf(red[2], red[3]));

    float sum = 0.f;
#pragma unroll
    for (int i = 0; i < 16; ++i) {
      float e = __expf(v[i] - mx);
      v[i] = e;
      sum += e;
    }
#pragma unroll
    for (int off = 32; off >= 1; off >>= 1) sum += __shfl_xor(sum, off, 64);
    if (l == 0) red[4 + w] = sum;
    __syncthreads();
    sum = red[4] + red[5] + red[6] + red[7];
    const float inv = 1.f / sum;

#pragma unroll
    for (int s = 0; s < 2; ++s) {
      const int j = tid * 8 + s * 2048;
      if (j < Lp) {
        u16x8 pk;
#pragma unroll
        for (int e = 0; e < 8; ++e) pk[e] = f2bf(v[s * 8 + e] * inv);
        *reinterpret_cast<u16x8*>(Sp + (tri + (j >> 7)) * 16384 + rr * 128 + (j & 127)) = pk;
      }
    }
    __syncthreads();
  }
}

// ---------------- Kernel 5: O += P @ V, split-K 1024-key segments ------------
// grid (80, 8). LPT decode: sx<52 -> full 32-step segments (mt asc); sx>=52 ->
// the 28 short remainder segments. Long blocks dispatch first (x varies
// fastest) -> better makespan. mt<=7 tiles have ns==1 -> plain store, no
// memset needed for rows < 1024.
__global__ __launch_bounds__(256) void pv_gemm(const u16* __restrict__ Sp,
                                               const u16* __restrict__ vT,
                                               float* __restrict__ out) {
  __shared__ u16 lds_[16384];
  const int nt = blockIdx.y;
  const int sx = blockIdx.x;
  int mt, ls;
  if (sx < 52) {            // full 1024-key segments
    int m = 0, c = 0;
    for (;;) {
      const int f = (m + 1) >> 3;
      if (sx < c + f) { ls = sx - c; break; }
      c += f; ++m;
    }
    mt = m;
  } else {                  // remainder segments (mt with (mt+1)%8 != 0)
    const int r = sx - 52;
    int m = 0, c = 0;
    for (;;) {
      if (((m + 1) & 7) != 0) { if (c == r) break; ++c; }
      ++m;
    }
    mt = m;
    ls = (mt + 1) >> 3;
  }
  const int m0 = mt * 128, n0 = nt * 128;
  const int k0 = ls * 1024;
  const int kext = (mt + 1) * 128;
  const int kend = (k0 + 1024 < kext) ? (k0 + 1024) : kext;
  const int ksteps = (kend - k0) >> 5;
  const size_t tri = (size_t)mt * (mt + 1) / 2;

  const int tid = threadIdx.x;
  const int w = tid >> 6, l = tid & 63;
  const int wr = (w >> 1) * 64, wc = (w & 1) * 64;
  const int lg = l >> 4, lr = l & 15;

  f32x4 acc[4][4];
#pragma unroll
  for (int i = 0; i < 4; ++i)
#pragma unroll
    for (int j = 0; j < 4; ++j) acc[i][j] = (f32x4){0.f, 0.f, 0.f, 0.f};

#define PA_SRC(t) (Sp + (tri + ((k0 + (t)*32) >> 7)) * 16384 + ((k0 + (t)*32) & 127))
#define PB_SRC(t) (vT + (size_t)n0 * SEQ + k0 + (t)*32)
  KLOOP2(ksteps, PA_SRC, 128, PB_SRC, SEQ);
#undef PA_SRC
#undef PB_SRC

  if (mt <= 7) {  // single segment: exclusive ownership, plain store
#pragma unroll
    for (int mb = 0; mb < 4; ++mb)
#pragma unroll
      for (int nb = 0; nb < 4; ++nb) {
        const int col = n0 + wc + nb * 16 + lr;
#pragma unroll
        for (int e = 0; e < 4; ++e) {
          const int row = m0 + wr + mb * 16 + lg * 4 + e;
          out[(size_t)row * EMBED + col] = acc[mb][nb][e];
        }
      }
  } else {
#pragma unroll
    for (int mb = 0; mb < 4; ++mb)
#pragma unroll
      for (int nb = 0; nb < 4; ++nb) {
        const int col = n0 + wc + nb * 16 + lr;
#pragma unroll
        for (int e = 0; e < 4; ++e) {
          const int row = m0 + wr + mb * 16 + lg * 4 + e;
          unsafeAtomicAdd(&out[(size_t)row * EMBED + col], acc[mb][nb][e]);
        }
      }
  }
}

// ---------------- Fallback flash attention (small ws) ------------------------
__global__ __launch_bounds__(512) void attn_fb(const u16* __restrict__ qkv,
                                               const u16* __restrict__ vT,
                                               float* __restrict__ out) {
  __shared__ u16 q_lds[16][1032];
  __shared__ u16 kv_lds[8][3][2048];
  __shared__ u16 p_lds[16][136];
  __shared__ float redmax[8][16];
  __shared__ float redsum[8][16];
  const int bid = blockIdx.x;
  const int tid = threadIdx.x;
  const int w = tid >> 6, l = tid & 63;
  const int lg = l >> 4, lr = l & 15;

  const int sr = l >> 4;
  const int scb = (l & 15) * 16;
  const int scolA = ((scb ^ (sr << 4)) >> 1);
  const int scolB = ((scb ^ ((4 + sr) << 4)) >> 1);
  int boff[4];
#pragma unroll
  for (int kk = 0; kk < 4; ++kk)
    boff[kk] = lr * 256 + ((kk * 64 + lg * 16) ^ ((lr & 7) << 4));

  u16* kvb[3] = {&kv_lds[w][0][0], &kv_lds[w][1][0], &kv_lds[w][2][0]};

#define STAGE_K(dc, bufp)                                                     \
  {                                                                           \
    LGKM0;                                                                    \
    const u16* g0 = qkv + (size_t)(kb + w * 16 + sr) * NQKV + EMBED + (dc) * 128; \
    gl2lds(g0 + scolA, (bufp));                                               \
    gl2lds(g0 + 4 * NQKV + scolB, (bufp) + 512);                              \
    gl2lds(g0 + 8 * NQKV + scolA, (bufp) + 1024);                             \
    gl2lds(g0 + 12 * NQKV + scolB, (bufp) + 1536);                            \
  }
#define STAGE_V(j, bufp)                                                      \
  {                                                                           \
    LGKM0;                                                                    \
    const u16* g0 = vT + (size_t)((j) * 128 + w * 16 + sr) * SEQ + kb;        \
    gl2lds(g0 + scolA, (bufp));                                               \
    gl2lds(g0 + 4 * SEQ + scolB, (bufp) + 512);                               \
    gl2lds(g0 + 8 * SEQ + scolA, (bufp) + 1024);                              \
    gl2lds(g0 + 12 * SEQ + scolB, (bufp) + 1536);                             \
  }

  const int qb = bid * 16;
  __syncthreads();
#pragma unroll
  for (int p = 0; p < 4; ++p) {
    int idx = p * 512 + tid;
    int r = idx >> 7, c = (idx & 127) * 8;
    *reinterpret_cast<u16x8*>(&q_lds[r][c]) =
        *reinterpret_cast<const u16x8*>(&qkv[(size_t)(qb + r) * NQKV + c]);
  }
  __syncthreads();
  s16x8 qf[32];
#pragma unroll
  for (int kk = 0; kk < 32; ++kk)
    qf[kk] = *reinterpret_cast<const s16x8*>(&q_lds[lr][kk * 32 + lg * 8]);

  f32x4 o_acc[8];
#pragma unroll
  for (int j = 0; j < 8; ++j) o_acc[j] = (f32x4){0.f, 0.f, 0.f, 0.f};
  float m_st[4], l_st[4];
#pragma unroll
  for (int e = 0; e < 4; ++e) { m_st[e] = -__builtin_inff(); l_st[e] = 0.f; }

  const int n_it = (qb >> 7) + 1;
  for (int it = 0; it < n_it; ++it) {
    const int kb = it << 7;
    const int kcol = kb + w * 16 + lr;

    f32x4 s = (f32x4){0.f, 0.f, 0.f, 0.f};
    STAGE_K(0, kvb[0]);
    STAGE_K(1, kvb[1]);
#pragma unroll
    for (int dc = 0; dc < 8; ++dc) {
      if (dc < 6) {
        STAGE_K(dc + 2, kvb[(dc + 2) % 3]);
      } else if (dc == 6) {
        STAGE_V(0, kvb[2]);
      } else {
        STAGE_V(1, kvb[0]);
      }
      WAITVM(8);
      u16* cur = kvb[dc % 3];
#pragma unroll
      for (int kk = 0; kk < 4; ++kk) {
        s16x8 bfr = *reinterpret_cast<const s16x8*>((const char*)cur + boff[kk]);
        s = mfma16(qf[dc * 4 + kk], bfr, s);
      }
    }

    float sv[4], mx[4];
#pragma unroll
    for (int e = 0; e < 4; ++e) {
      float v = s[e] * 0.03125f;
      sv[e] = (kcol > qb + lg * 4 + e) ? -__builtin_inff() : v;
      mx[e] = sv[e];
    }
#pragma unroll
    for (int off = 1; off < 16; off <<= 1)
#pragma unroll
      for (int e = 0; e < 4; ++e) mx[e] = fmaxf(mx[e], __shfl_xor(mx[e], off, 64));
    if (lr == 0) {
#pragma unroll
      for (int e = 0; e < 4; ++e) redmax[w][lg * 4 + e] = mx[e];
    }
    BAR();

    float m_new[4], sc[4], pv[4], rs[4];
#pragma unroll
    for (int e = 0; e < 4; ++e) {
      float m = m_st[e];
#pragma unroll
      for (int ww = 0; ww < 8; ++ww) m = fmaxf(m, redmax[ww][lg * 4 + e]);
      m_new[e] = m;
      sc[e] = __expf(m_st[e] - m);
      pv[e] = __expf(sv[e] - m);
      rs[e] = pv[e];
    }
#pragma unroll
    for (int off = 1; off < 16; off <<= 1)
#pragma unroll
      for (int e = 0; e < 4; ++e) rs[e] += __shfl_xor(rs[e], off, 64);
    if (lr == 0) {
#pragma unroll
      for (int e = 0; e < 4; ++e) redsum[w][lg * 4 + e] = rs[e];
    }
#pragma unroll
    for (int e = 0; e < 4; ++e) p_lds[lg * 4 + e][w * 16 + lr] = f2bf(pv[e]);
    BAR();

#pragma unroll
    for (int e = 0; e < 4; ++e) {
      float a2 = l_st[e] * sc[e];
#pragma unroll
      for (int ww = 0; ww < 8; ++ww) a2 += redsum[ww][lg * 4 + e];
      l_st[e] = a2;
      m_st[e] = m_new[e];
    }
#pragma unroll
    for (int j = 0; j < 8; ++j)
#pragma unroll
      for (int e = 0; e < 4; ++e) o_acc[j][e] *= sc[e];

    s16x8 pa[4];
#pragma unroll
    for (int kk = 0; kk < 4; ++kk)
      pa[kk] = *reinterpret_cast<const s16x8*>(&p_lds[lr][kk * 32 + lg * 8]);

#pragma unroll
    for (int j = 0; j < 8; ++j) {
      if (j < 6) {
        STAGE_V(j + 2, kvb[(j + 4) % 3]);
        WAITVM(8);
      } else if (j == 6) {
        WAITVM(4);
      } else {
        WAITVM(0);
      }
      u16* cur = kvb[(j + 2) % 3];
#pragma unroll
      for (int kk = 0; kk < 4; ++kk) {
        s16x8 bfr = *reinterpret_cast<const s16x8*>((const char*)cur + boff[kk]);
        o_acc[j] = mfma16(pa[kk], bfr, o_acc[j]);
      }
    }
  }

#pragma unroll
  for (int j = 0; j < 8; ++j) {
    const int col = j * 128 + w * 16 + lr;
#pragma unroll
    for (int e = 0; e < 4; ++e)
      out[(size_t)(qb + lg * 4 + e) * EMBED + col] = o_acc[j][e] / l_st[e];
  }
#undef STAGE_K
#undef STAGE_V
}

extern "C" void kernel_launch(void* const* d_in, const int* in_sizes, int n_in,
                              void* d_out, int out_size, void* d_ws, size_t ws_size,
                              hipStream_t stream) {
  (void)in_sizes; (void)n_in; (void)out_size;
  const float* x = (const float*)d_in[0];
  const float* W = (const float*)d_in[1];
  const float* bias = (const float*)d_in[2];
  float* out = (float*)d_out;

  u16* qkv = (u16*)d_ws;                               // [0,24) MB
  u16* vT = qkv + (size_t)SEQ * NQKV;                  // [24,32) MB
  u16* wT = (u16*)d_out;                               // d_out[0,6) MB scratch (dead after qkv_gemm)
  u16* Sp = (u16*)((char*)d_ws + (32u << 20));         // [32, 48.5) MB packed S/P

  const size_t need = (32u << 20) + (size_t)528 * 16384 * 2;
  const bool big = ws_size >= need;
  // xbf must not alias vT (qkv_gemm reads xbf while writing vT).
  u16* xbf = big ? Sp : (u16*)((char*)d_out + (8u << 20));

  conv_fused<<<1792, 256, 0, stream>>>(x, W, xbf, (u16*)d_out);
  qkv_gemm<<<(SEQ / 128) * (NQKV / 128), 256, 0, stream>>>(xbf, wT, bias, qkv, vT);

  if (big) {
    s_gemm<<<528, 256, 0, stream>>>(qkv, Sp);
    softmax_rows<<<2048, 256, 0, stream>>>(Sp);
    // rows >= 1024 receive atomics from multi-segment tiles; rows < 1024 are
    // written exactly once with plain stores.
    hipMemsetAsync((char*)d_out + (size_t)1024 * EMBED * sizeof(float), 0,
                   (size_t)(SEQ - 1024) * EMBED * sizeof(float), stream);
    pv_gemm<<<dim3(80, 8), 256, 0, stream>>>(Sp, vT, out);
  } else {
    attn_fb<<<SEQ / 16, 512, 0, stream>>>(qkv, vT, out);
  }
}